// Round 1
// baseline (722.862 us; speedup 1.0000x reference)
//
#include <hip/hip_runtime.h>
#include <stdint.h>

#define NB 4
#define NS 2048
#define ND 1024
#define NH 16
#define NDK 64
#define L2E 1.44269504088896340736f

typedef __attribute__((ext_vector_type(8))) short     s16x8;
typedef __attribute__((ext_vector_type(4))) float     f32x4;
typedef __attribute__((ext_vector_type(4))) unsigned  u32x4;

__device__ __forceinline__ unsigned short f2bf(float f) {
    union { float f; unsigned u; } v; v.f = f;
    unsigned r = v.u + 0x7FFFu + ((v.u >> 16) & 1u);   // round-to-nearest-even
    return (unsigned short)(r >> 16);
}

// ---------------------------------------------------------------- dtype probe
// If x is bf16 data, word's low 16 bits are a bf16 value of ~N(0,2): exponent
// in [100,140] essentially always. If x is f32, low 16 bits are random
// mantissa bits: exponent-sane probability ~0.16. Count over 1024 words.
__global__ void detect_dtype(const unsigned* __restrict__ x, int* __restrict__ flag) {
    int lane = threadIdx.x;
    int cnt = 0;
    for (int i = lane; i < 1024; i += 64) {
        unsigned lo = x[i] & 0xFFFFu;
        unsigned e  = (lo >> 7) & 0xFFu;
        cnt += (e >= 100u && e <= 140u) ? 1 : 0;
    }
    for (int d = 1; d < 64; d <<= 1) cnt += __shfl_xor(cnt, d);
    if (lane == 0) flag[0] = (cnt > 512) ? 1 : 0;  // 1 = bf16 inputs
}

// ---------------------------------------------------------------- GEMM
// C[M][N] = sum_k A[m][k] * W[n][k]   (both row-major, ld = 1024 = K)
// Tile 128x128, BK=32, 4 waves (2x2), per-wave 64x64 via 4x4 16x16x32 MFMA.
// LDS tiles padded 32->40 elems/row to break bank conflicts on ds_read_b128.
__device__ __forceinline__ void stage_tile(unsigned short* lds, const void* src,
                                           long ld, long r0, long k0, int dt, int tid) {
#pragma unroll
    for (int h = 0; h < 2; ++h) {
        int c    = tid + h * 256;        // 0..511 chunks of 8 elems
        int row  = c >> 2;               // 128 rows
        int col8 = (c & 3) * 8;          // 0,8,16,24
        long off = (r0 + row) * ld + k0 + col8;
        u32x4 v;
        if (dt) {
            v = *(const u32x4*)((const unsigned short*)src + off);
        } else {
            const float* p = (const float*)src + off;
            f32x4 a = *(const f32x4*)p;
            f32x4 b = *(const f32x4*)(p + 4);
            v[0] = (unsigned)f2bf(a[0]) | ((unsigned)f2bf(a[1]) << 16);
            v[1] = (unsigned)f2bf(a[2]) | ((unsigned)f2bf(a[3]) << 16);
            v[2] = (unsigned)f2bf(b[0]) | ((unsigned)f2bf(b[1]) << 16);
            v[3] = (unsigned)f2bf(b[2]) | ((unsigned)f2bf(b[3]) << 16);
        }
        *(u32x4*)(lds + row * 40 + col8) = v;
    }
}

// OUT_MODE 0: bf16 -> dst[b][h][s][dk]   (m = b*S+s, n = h*64+dk)
// OUT_MODE 1: bf16 -> dst[b][h][dk][s]   (m = h*64+dk, n = b*S+s)  [V^T]
// OUT_MODE 2: f32 or bf16 (per flag) -> dst[m*1024+n]
template<int OUT_MODE>
__global__ __launch_bounds__(256, 2)
void gemm_bt(const void* __restrict__ A, const void* __restrict__ W,
             void* __restrict__ dst, const int* __restrict__ flagp,
             int aForce, int wForce, float scale)
{
    __shared__ unsigned short As[128 * 40];
    __shared__ unsigned short Bs[128 * 40];
    const long K = 1024;
    int tid  = threadIdx.x;
    int w    = tid >> 6, lane = tid & 63;
    int wr   = w >> 1,   wc   = w & 1;
    long m0  = (long)blockIdx.y * 128;
    long n0  = (long)blockIdx.x * 128;
    int fl   = *flagp;
    int adt  = aForce ? 1 : fl;
    int wdt  = wForce ? 1 : fl;

    f32x4 zero4 = {0.f, 0.f, 0.f, 0.f};
    f32x4 acc[4][4];
#pragma unroll
    for (int i = 0; i < 4; ++i)
#pragma unroll
        for (int j = 0; j < 4; ++j) acc[i][j] = zero4;

    int lr = lane & 15, lk = (lane >> 4) * 8;

    for (long k0 = 0; k0 < K; k0 += 32) {
        __syncthreads();
        stage_tile(As, A, K, m0, k0, adt, tid);
        stage_tile(Bs, W, K, n0, k0, wdt, tid);
        __syncthreads();
        s16x8 af[4], bf[4];
#pragma unroll
        for (int i = 0; i < 4; ++i)
            af[i] = *(const s16x8*)(As + (wr * 64 + i * 16 + lr) * 40 + lk);
#pragma unroll
        for (int j = 0; j < 4; ++j)
            bf[j] = *(const s16x8*)(Bs + (wc * 64 + j * 16 + lr) * 40 + lk);
#pragma unroll
        for (int i = 0; i < 4; ++i)
#pragma unroll
            for (int j = 0; j < 4; ++j)
                acc[i][j] = __builtin_amdgcn_mfma_f32_16x16x32_bf16(af[i], bf[j], acc[i][j], 0, 0, 0);
    }

    int rbase = (lane >> 4) * 4;
#pragma unroll
    for (int i = 0; i < 4; ++i)
#pragma unroll
        for (int j = 0; j < 4; ++j)
#pragma unroll
            for (int r = 0; r < 4; ++r) {
                long m = m0 + wr * 64 + i * 16 + rbase + r;
                long n = n0 + wc * 64 + j * 16 + lr;
                float v = acc[i][j][r] * scale;
                if (OUT_MODE == 0) {
                    long b = m >> 11, s = m & 2047, hh = n >> 6, dk = n & 63;
                    ((unsigned short*)dst)[(((b * NH + hh) * NS) + s) * NDK + dk] = f2bf(v);
                } else if (OUT_MODE == 1) {
                    long hh = m >> 6, dk = m & 63, b = n >> 11, s = n & 2047;
                    ((unsigned short*)dst)[(((b * NH + hh) * NDK) + dk) * NS + s] = f2bf(v);
                } else {
                    if (fl) ((unsigned short*)dst)[m * 1024 + n] = f2bf(v);
                    else    ((float*)dst)[m * 1024 + n] = v;
                }
            }
}

// ---------------------------------------------------------------- attention
// Q:[B,H,S,64] bf16 (pre-scaled by 1/8), K:[B,H,S,64] bf16, Vt:[B,H,64,S] bf16.
// One wave per 16-row Q block; 4 independent waves per 256-thread block.
// KV step = 32 keys: S = Q*K^T via 2x2 MFMA, wave-parallel online softmax,
// P staged bf16 through (double-buffered, padded) LDS, PV via 4 MFMA.
__global__ __launch_bounds__(256)
void attn_fwd(const unsigned short* __restrict__ Q,
              const unsigned short* __restrict__ Kt,
              const unsigned short* __restrict__ Vt,
              unsigned short* __restrict__ Oo,
              const int* __restrict__ causalp)
{
    __shared__ unsigned short P[4][2][16 * 40];
    int tid  = threadIdx.x;
    int w    = tid >> 6, lane = tid & 63;
    int bh   = blockIdx.y;                // 0..63
    long qbase = ((long)blockIdx.x * 4 + w) * 16;
    const unsigned short* Qh = Q  + (long)bh * NS * NDK;
    const unsigned short* Kh = Kt + (long)bh * NS * NDK;
    const unsigned short* Vh = Vt + (long)bh * NDK * NS;
    int causal = *causalp;
    int lr = lane & 15, lkg = lane >> 4;
    int rbase = lkg * 4;

    s16x8 qf0, qf1;
    {
        const unsigned short* p = Qh + (qbase + lr) * NDK + lkg * 8;
        qf0 = *(const s16x8*)p;
        qf1 = *(const s16x8*)(p + 32);
    }

    f32x4 zero4 = {0.f, 0.f, 0.f, 0.f};
    f32x4 o[4];
#pragma unroll
    for (int j = 0; j < 4; ++j) o[j] = zero4;
    float mrow[4] = {-1e30f, -1e30f, -1e30f, -1e30f};
    float lrow[4] = {0.f, 0.f, 0.f, 0.f};

    long kv_end = causal ? (qbase + 16) : (long)NS;

    int it = 0;
    for (long kv0 = 0; kv0 < kv_end; kv0 += 32, ++it) {
        // ---- S = Q K^T (scaled already)
        f32x4 st[2];
#pragma unroll
        for (int ct = 0; ct < 2; ++ct) {
            const unsigned short* kp = Kh + (kv0 + ct * 16 + lr) * NDK + lkg * 8;
            s16x8 kf0 = *(const s16x8*)kp;
            s16x8 kf1 = *(const s16x8*)(kp + 32);
            f32x4 z = zero4;
            z = __builtin_amdgcn_mfma_f32_16x16x32_bf16(qf0, kf0, z, 0, 0, 0);
            st[ct] = __builtin_amdgcn_mfma_f32_16x16x32_bf16(qf1, kf1, z, 0, 0, 0);
        }
        // ---- causal mask (diagonal-crossing tiles only)
        if (causal && (kv0 + 31 >= qbase)) {
#pragma unroll
            for (int ct = 0; ct < 2; ++ct)
#pragma unroll
                for (int r = 0; r < 4; ++r) {
                    long q  = qbase + rbase + r;
                    long ky = kv0 + ct * 16 + lr;
                    if (ky > q) st[ct][r] = -1e30f;
                }
        }
        // ---- online softmax (rows live on (lane>>4)*4+r; cols across 16 lanes)
        float tmax[4], tsum[4];
#pragma unroll
        for (int r = 0; r < 4; ++r) tmax[r] = fmaxf(st[0][r], st[1][r]);
#pragma unroll
        for (int d = 1; d < 16; d <<= 1)
#pragma unroll
            for (int r = 0; r < 4; ++r) tmax[r] = fmaxf(tmax[r], __shfl_xor(tmax[r], d));
        float al[4];
#pragma unroll
        for (int r = 0; r < 4; ++r) {
            float mn = fmaxf(mrow[r], tmax[r]);
            al[r] = exp2f((mrow[r] - mn) * L2E);
            mrow[r] = mn;
        }
        f32x4 p0, p1;
#pragma unroll
        for (int r = 0; r < 4; ++r) {
            p0[r] = exp2f((st[0][r] - mrow[r]) * L2E);
            p1[r] = exp2f((st[1][r] - mrow[r]) * L2E);
            tsum[r] = p0[r] + p1[r];
        }
#pragma unroll
        for (int d = 1; d < 16; d <<= 1)
#pragma unroll
            for (int r = 0; r < 4; ++r) tsum[r] += __shfl_xor(tsum[r], d);
#pragma unroll
        for (int r = 0; r < 4; ++r) lrow[r] = lrow[r] * al[r] + tsum[r];
#pragma unroll
        for (int j = 0; j < 4; ++j)
#pragma unroll
            for (int r = 0; r < 4; ++r) o[j][r] *= al[r];
        // ---- P -> LDS (bf16), cross-lane redistribute to A-fragment layout
        unsigned short* Pb = &P[w][it & 1][0];
#pragma unroll
        for (int r = 0; r < 4; ++r) {
            Pb[(rbase + r) * 40 + lr]      = f2bf(p0[r]);
            Pb[(rbase + r) * 40 + 16 + lr] = f2bf(p1[r]);
        }
        asm volatile("s_waitcnt lgkmcnt(0)" ::: "memory");
        __builtin_amdgcn_sched_barrier(0);
        s16x8 pf = *(const s16x8*)(Pb + lr * 40 + lkg * 8);
        // ---- O += P * V   (Vt gives contiguous B-fragments)
#pragma unroll
        for (int j = 0; j < 4; ++j) {
            const unsigned short* vp = Vh + (j * 16 + lr) * NS + kv0 + lkg * 8;
            s16x8 vf = *(const s16x8*)vp;
            o[j] = __builtin_amdgcn_mfma_f32_16x16x32_bf16(pf, vf, o[j], 0, 0, 0);
        }
    }

    float inv[4];
#pragma unroll
    for (int r = 0; r < 4; ++r) inv[r] = 1.0f / lrow[r];
    long b = bh >> 4, hh = bh & 15;
#pragma unroll
    for (int j = 0; j < 4; ++j)
#pragma unroll
        for (int r = 0; r < 4; ++r) {
            long q = qbase + rbase + r;
            Oo[((b * NS + q) * ND) + hh * NDK + j * 16 + lr] = f2bf(o[j][r] * inv[r]);
        }
}

// ---------------------------------------------------------------- launch
extern "C" void kernel_launch(void* const* d_in, const int* in_sizes, int n_in,
                              void* d_out, int out_size, void* d_ws, size_t ws_size,
                              hipStream_t stream) {
    const void* x  = d_in[0];
    const void* Wq = d_in[1];
    const void* Wk = d_in[2];
    const void* Wv = d_in[3];
    const void* Wo = d_in[4];
    const int* causal = (const int*)d_in[5];

    const long MK = (long)NB * NS;           // 8192
    const long TOK = MK * ND;                // 8.39M elems per tensor
    size_t need = 256 + 4UL * TOK * 2;       // flag + Q,K,Vt,AO (bf16)
    if (ws_size < need) return;

    char* ws = (char*)d_ws;
    int* flag = (int*)ws;
    unsigned short* Qb = (unsigned short*)(ws + 256);
    unsigned short* Kb = Qb + TOK;
    unsigned short* Vb = Kb + TOK;
    unsigned short* Ab = Vb + TOK;

    detect_dtype<<<1, 64, 0, stream>>>((const unsigned*)x, flag);

    dim3 blk(256);
    // Q projection (pre-scale by 1/sqrt(DK)=0.125), K projection
    gemm_bt<0><<<dim3(8, 64), blk, 0, stream>>>(x, Wq, Qb, flag, 0, 0, 0.125f);
    gemm_bt<0><<<dim3(8, 64), blk, 0, stream>>>(x, Wk, Kb, flag, 0, 0, 1.0f);
    // V projection, operands swapped -> writes V^T [B,H,64,S]
    gemm_bt<1><<<dim3(64, 8), blk, 0, stream>>>(Wv, x, Vb, flag, 0, 0, 1.0f);
    // attention
    attn_fwd<<<dim3(32, 64), blk, 0, stream>>>(Qb, Kb, Vb, Ab, causal);
    // output projection
    gemm_bt<2><<<dim3(8, 64), blk, 0, stream>>>(Ab, Wo, d_out, flag, 1, 0, 1.0f);
}

// Round 2
// 412.766 us; speedup vs baseline: 1.7513x; 1.7513x over previous
//
#include <hip/hip_runtime.h>
#include <stdint.h>

#define NB 4
#define NS 2048
#define ND 1024
#define NH 16
#define NDK 64
#define L2E 1.44269504088896340736f

typedef __attribute__((ext_vector_type(8)))  short     s16x8;
typedef __attribute__((ext_vector_type(4)))  float     f32x4;
typedef __attribute__((ext_vector_type(16))) float     f32x16;
typedef __attribute__((ext_vector_type(4)))  unsigned  u32x4;

__device__ __forceinline__ unsigned short f2bf(float f) {
    union { float f; unsigned u; } v; v.f = f;
    unsigned r = v.u + 0x7FFFu + ((v.u >> 16) & 1u);
    return (unsigned short)(r >> 16);
}
__device__ __forceinline__ unsigned cvt_pk_bf16(float lo, float hi) {
    unsigned r;
    asm("v_cvt_pk_bf16_f32 %0, %1, %2" : "=v"(r) : "v"(lo), "v"(hi));
    return r;
}
// v_permlane32_swap_b32: a.hi-lanes <-> b.lo-lanes. After: a = {a_lo, b_lo-of-partner...}
// precisely a'[i>=32]=b[i-32], b'[i<32]=a[i+32]; both outputs used.
__device__ __forceinline__ void pl32swap(unsigned &a, unsigned &b) {
    asm volatile("v_permlane32_swap_b32 %0, %1" : "+v"(a), "+v"(b));
}
__device__ __forceinline__ f32x16 fz16() {
    f32x16 z;
#pragma unroll
    for (int r = 0; r < 16; ++r) z[r] = 0.f;
    return z;
}

// ---------------------------------------------------------------- dtype probe
__global__ void detect_dtype(const unsigned* __restrict__ x, int* __restrict__ flag) {
    int lane = threadIdx.x;
    int cnt = 0;
    for (int i = lane; i < 1024; i += 64) {
        unsigned lo = x[i] & 0xFFFFu;
        unsigned e  = (lo >> 7) & 0xFFu;
        cnt += (e >= 100u && e <= 140u) ? 1 : 0;
    }
    for (int d = 1; d < 64; d <<= 1) cnt += __shfl_xor(cnt, d);
    if (lane == 0) flag[0] = (cnt > 512) ? 1 : 0;  // 1 = bf16 inputs
}

// ---------------------------------------------------------------- GEMM
// C[M][N] = sum_k A[m][k] * W[n][k], 128x128 tile, BK=32, 4 waves.
__device__ __forceinline__ void stage_tile(unsigned short* lds, const void* src,
                                           long ld, long r0, long k0, int dt, int tid) {
#pragma unroll
    for (int h = 0; h < 2; ++h) {
        int c    = tid + h * 256;
        int row  = c >> 2;
        int col8 = (c & 3) * 8;
        long off = (r0 + row) * ld + k0 + col8;
        u32x4 v;
        if (dt) {
            v = *(const u32x4*)((const unsigned short*)src + off);
        } else {
            const float* p = (const float*)src + off;
            f32x4 a = *(const f32x4*)p;
            f32x4 b = *(const f32x4*)(p + 4);
            v[0] = cvt_pk_bf16(a[0], a[1]);
            v[1] = cvt_pk_bf16(a[2], a[3]);
            v[2] = cvt_pk_bf16(b[0], b[1]);
            v[3] = cvt_pk_bf16(b[2], b[3]);
        }
        *(u32x4*)(lds + row * 40 + col8) = v;
    }
}

template<int OUT_MODE>
__global__ __launch_bounds__(256, 2)
void gemm_bt(const void* __restrict__ A, const void* __restrict__ W,
             void* __restrict__ dst, const int* __restrict__ flagp,
             int aForce, int wForce, float scale)
{
    __shared__ unsigned short As[128 * 40];
    __shared__ unsigned short Bs[128 * 40];
    const long K = 1024;
    int tid  = threadIdx.x;
    int w    = tid >> 6, lane = tid & 63;
    int wr   = w >> 1,   wc   = w & 1;
    long m0  = (long)blockIdx.y * 128;
    long n0  = (long)blockIdx.x * 128;
    int fl   = *flagp;
    int adt  = aForce ? 1 : fl;
    int wdt  = wForce ? 1 : fl;

    f32x4 zero4 = {0.f, 0.f, 0.f, 0.f};
    f32x4 acc[4][4];
#pragma unroll
    for (int i = 0; i < 4; ++i)
#pragma unroll
        for (int j = 0; j < 4; ++j) acc[i][j] = zero4;

    int lr = lane & 15, lk = (lane >> 4) * 8;

    for (long k0 = 0; k0 < K; k0 += 32) {
        __syncthreads();
        stage_tile(As, A, K, m0, k0, adt, tid);
        stage_tile(Bs, W, K, n0, k0, wdt, tid);
        __syncthreads();
        s16x8 af[4], bf[4];
#pragma unroll
        for (int i = 0; i < 4; ++i)
            af[i] = *(const s16x8*)(As + (wr * 64 + i * 16 + lr) * 40 + lk);
#pragma unroll
        for (int j = 0; j < 4; ++j)
            bf[j] = *(const s16x8*)(Bs + (wc * 64 + j * 16 + lr) * 40 + lk);
#pragma unroll
        for (int i = 0; i < 4; ++i)
#pragma unroll
            for (int j = 0; j < 4; ++j)
                acc[i][j] = __builtin_amdgcn_mfma_f32_16x16x32_bf16(af[i], bf[j], acc[i][j], 0, 0, 0);
    }

    int rbase = (lane >> 4) * 4;
#pragma unroll
    for (int i = 0; i < 4; ++i)
#pragma unroll
        for (int j = 0; j < 4; ++j)
#pragma unroll
            for (int r = 0; r < 4; ++r) {
                long m = m0 + wr * 64 + i * 16 + rbase + r;
                long n = n0 + wc * 64 + j * 16 + lr;
                float v = acc[i][j][r] * scale;
                if (OUT_MODE == 0) {
                    long b = m >> 11, s = m & 2047, hh = n >> 6, dk = n & 63;
                    ((unsigned short*)dst)[(((b * NH + hh) * NS) + s) * NDK + dk] = f2bf(v);
                } else if (OUT_MODE == 1) {
                    long hh = m >> 6, dk = m & 63, b = n >> 11, s = n & 2047;
                    ((unsigned short*)dst)[(((b * NH + hh) * NDK) + dk) * NS + s] = f2bf(v);
                } else {
                    if (fl) ((unsigned short*)dst)[m * 1024 + n] = f2bf(v);
                    else    ((float*)dst)[m * 1024 + n] = v;
                }
            }
}

// ---------------------------------------------------------------- attention v2
// Swapped-operand 32x32 flash attention (guide §B / T12 / T13).
// S^T = mfma(K,Q): lane owns q = qbase + (lane&31); 16 k-values in-register.
// P -> bf16 via cvt_pk, redistributed to PV B-fragment via 4 permlane32_swap.
// O^T = mfma(V^T, P^T): accumulator stays in q=lane&31 domain (no cross-lane
// rescale). Causal balance: block i's 4 waves take tiles {2i,2i+1,62-2i,63-2i}
// -> every block does exactly 130 tile-iterations.
__global__ __launch_bounds__(256)
void attn_fwd2(const unsigned short* __restrict__ Q,
               const unsigned short* __restrict__ Kt,
               const unsigned short* __restrict__ Vt,
               unsigned short* __restrict__ Oo,
               const int* __restrict__ causalp)
{
    __shared__ unsigned short ep[4][32 * 72];
    int tid  = threadIdx.x;
    int w    = tid >> 6, lane = tid & 63;
    int l31  = lane & 31, hi = lane >> 5;
    int bh   = blockIdx.y;
    int i    = blockIdx.x;                      // 0..15
    int tile = (w < 2) ? (2 * i + w) : (62 - 2 * i + (w & 1));
    long qbase = (long)tile * 32;
    int causal = *causalp;

    const unsigned short* Qh = Q  + (long)bh * NS * NDK;
    const unsigned short* Kh = Kt + (long)bh * NS * NDK;
    const unsigned short* Vh = Vt + (long)bh * NDK * NS;

    s16x8 qf[4];
#pragma unroll
    for (int kd = 0; kd < 4; ++kd)
        qf[kd] = *(const s16x8*)(Qh + (qbase + l31) * NDK + kd * 16 + hi * 8);

    f32x16 o0 = fz16(), o1 = fz16();
    float mrow = -1e30f, lrow = 0.f;

    long kv_end = causal ? (qbase + 32) : (long)NS;

    for (long kv0 = 0; kv0 < kv_end; kv0 += 32) {
        // ---- loads (K rows + V^T rows) -------------------------------------
        s16x8 kf[4];
#pragma unroll
        for (int kd = 0; kd < 4; ++kd)
            kf[kd] = *(const s16x8*)(Kh + (kv0 + l31) * NDK + kd * 16 + hi * 8);
        const unsigned short* v0p = Vh + (long)l31 * NS + kv0 + hi * 8;
        const unsigned short* v1p = Vh + (long)(32 + l31) * NS + kv0 + hi * 8;
        s16x8 va0 = *(const s16x8*)(v0p);
        s16x8 va1 = *(const s16x8*)(v0p + 16);
        s16x8 vb0 = *(const s16x8*)(v1p);
        s16x8 vb1 = *(const s16x8*)(v1p + 16);

        // ---- S^T = K * Q^T  (32k x 32q), chained over dk -------------------
        f32x16 st = fz16();
#pragma unroll
        for (int kd = 0; kd < 4; ++kd)
            st = __builtin_amdgcn_mfma_f32_32x32x16_bf16(kf[kd], qf[kd], st, 0, 0, 0);

        // ---- causal mask (only the diagonal tile kv0 == qbase) -------------
        if (causal && kv0 + 31 > qbase) {
#pragma unroll
            for (int r = 0; r < 16; ++r) {
                int krow = (r & 3) + 8 * (r >> 2) + 4 * hi;
                if (kv0 + krow > qbase + l31) st[r] = -1e30f;
            }
        }

        // ---- online softmax: in-lane + one cross-half shfl -----------------
        float tm = st[0];
#pragma unroll
        for (int r = 1; r < 16; ++r) tm = fmaxf(tm, st[r]);
        tm = fmaxf(tm, __shfl_xor(tm, 32));
        if (!__all(tm - mrow <= 8.0f)) {         // T13 defer-max
            float mnew = fmaxf(mrow, tm);
            float al = exp2f((mrow - mnew) * L2E);
            lrow *= al;
#pragma unroll
            for (int r = 0; r < 16; ++r) { o0[r] *= al; o1[r] *= al; }
            mrow = mnew;
        }
        float ps[16];
        float sum = 0.f;
#pragma unroll
        for (int r = 0; r < 16; ++r) {
            ps[r] = exp2f((st[r] - mrow) * L2E);
            sum += ps[r];
        }
        lrow += sum;                              // per-half partial; combined at end

        // ---- P -> bf16 PV-B-fragments: 8 cvt_pk + 4 permlane32_swap --------
        unsigned b0 = cvt_pk_bf16(ps[0],  ps[1]);
        unsigned b1 = cvt_pk_bf16(ps[2],  ps[3]);
        unsigned b2 = cvt_pk_bf16(ps[4],  ps[5]);
        unsigned b3 = cvt_pk_bf16(ps[6],  ps[7]);
        unsigned b4 = cvt_pk_bf16(ps[8],  ps[9]);
        unsigned b5 = cvt_pk_bf16(ps[10], ps[11]);
        unsigned b6 = cvt_pk_bf16(ps[12], ps[13]);
        unsigned b7 = cvt_pk_bf16(ps[14], ps[15]);
        pl32swap(b0, b2);  pl32swap(b1, b3);      // -> words 0,1 / 2,3 of pf0
        pl32swap(b4, b6);  pl32swap(b5, b7);      // -> pf1
        union { unsigned u[4]; s16x8 v; } pf0, pf1;
        pf0.u[0] = b0; pf0.u[1] = b1; pf0.u[2] = b2; pf0.u[3] = b3;
        pf1.u[0] = b4; pf1.u[1] = b5; pf1.u[2] = b6; pf1.u[3] = b7;

        // ---- O^T += V^T * P^T ---------------------------------------------
        o0 = __builtin_amdgcn_mfma_f32_32x32x16_bf16(va0, pf0.v, o0, 0, 0, 0);
        o0 = __builtin_amdgcn_mfma_f32_32x32x16_bf16(va1, pf1.v, o0, 0, 0, 0);
        o1 = __builtin_amdgcn_mfma_f32_32x32x16_bf16(vb0, pf0.v, o1, 0, 0, 0);
        o1 = __builtin_amdgcn_mfma_f32_32x32x16_bf16(vb1, pf1.v, o1, 0, 0, 0);
    }

    // ---- epilogue: normalize, transpose via LDS, coalesced store -----------
    lrow += __shfl_xor(lrow, 32);
    float inv = 1.0f / lrow;
    unsigned short* myep = &ep[w][0];
#pragma unroll
    for (int j = 0; j < 2; ++j) {
        const f32x16& o = j ? o1 : o0;
#pragma unroll
        for (int g = 0; g < 4; ++g) {
            int d0 = j * 32 + g * 8 + hi * 4;
            unsigned lo = cvt_pk_bf16(o[g * 4 + 0] * inv, o[g * 4 + 1] * inv);
            unsigned hw = cvt_pk_bf16(o[g * 4 + 2] * inv, o[g * 4 + 3] * inv);
            unsigned short* p = myep + l31 * 72 + d0;
            *(unsigned*)(p)     = lo;
            *(unsigned*)(p + 2) = hw;
        }
    }
    asm volatile("s_waitcnt lgkmcnt(0)" ::: "memory");
    __builtin_amdgcn_sched_barrier(0);
    long b = bh >> 4, hh = bh & 15;
#pragma unroll
    for (int rr = 0; rr < 4; ++rr) {
        int q2 = rr * 8 + (lane >> 3);
        int d2 = (lane & 7) * 8;
        u32x4 vv = *(const u32x4*)(myep + q2 * 72 + d2);
        *(u32x4*)(Oo + ((b * NS + qbase + q2) * ND) + hh * NDK + d2) = vv;
    }
}

// ---------------------------------------------------------------- launch
extern "C" void kernel_launch(void* const* d_in, const int* in_sizes, int n_in,
                              void* d_out, int out_size, void* d_ws, size_t ws_size,
                              hipStream_t stream) {
    const void* x  = d_in[0];
    const void* Wq = d_in[1];
    const void* Wk = d_in[2];
    const void* Wv = d_in[3];
    const void* Wo = d_in[4];
    const int* causal = (const int*)d_in[5];

    const long MK  = (long)NB * NS;
    const long TOK = MK * ND;
    size_t need = 256 + 4UL * TOK * 2;
    if (ws_size < need) return;

    char* ws = (char*)d_ws;
    int* flag = (int*)ws;
    unsigned short* Qb = (unsigned short*)(ws + 256);
    unsigned short* Kb = Qb + TOK;
    unsigned short* Vb = Kb + TOK;
    unsigned short* Ab = Vb + TOK;

    detect_dtype<<<1, 64, 0, stream>>>((const unsigned*)x, flag);

    dim3 blk(256);
    gemm_bt<0><<<dim3(8, 64), blk, 0, stream>>>(x, Wq, Qb, flag, 0, 0, 0.125f);
    gemm_bt<0><<<dim3(8, 64), blk, 0, stream>>>(x, Wk, Kb, flag, 0, 0, 1.0f);
    gemm_bt<1><<<dim3(64, 8), blk, 0, stream>>>(Wv, x, Vb, flag, 0, 0, 1.0f);
    attn_fwd2<<<dim3(16, 64), blk, 0, stream>>>(Qb, Kb, Vb, Ab, causal);
    gemm_bt<2><<<dim3(8, 64), blk, 0, stream>>>(Ab, Wo, d_out, flag, 1, 0, 1.0f);
}

// Round 3
// 280.910 us; speedup vs baseline: 2.5733x; 1.4694x over previous
//
#include <hip/hip_runtime.h>
#include <stdint.h>

#define NB 4
#define NS 2048
#define ND 1024
#define NH 16
#define NDK 64
#define L2E 1.44269504088896340736f

typedef __attribute__((ext_vector_type(8)))  short     s16x8;
typedef __attribute__((ext_vector_type(4)))  float     f32x4;
typedef __attribute__((ext_vector_type(16))) float     f32x16;
typedef __attribute__((ext_vector_type(4)))  unsigned  u32x4;

__device__ __forceinline__ unsigned short f2bf(float f) {
    union { float f; unsigned u; } v; v.f = f;
    unsigned r = v.u + 0x7FFFu + ((v.u >> 16) & 1u);
    return (unsigned short)(r >> 16);
}
__device__ __forceinline__ unsigned cvt_pk_bf16(float lo, float hi) {
    unsigned r;
    asm("v_cvt_pk_bf16_f32 %0, %1, %2" : "=v"(r) : "v"(lo), "v"(hi));
    return r;
}
__device__ __forceinline__ void pl32swap(unsigned &a, unsigned &b) {
    asm volatile("v_permlane32_swap_b32 %0, %1" : "+v"(a), "+v"(b));
}
__device__ __forceinline__ float exp2_hw(float x) {
    float r; asm("v_exp_f32 %0, %1" : "=v"(r) : "v"(x)); return r;
}
__device__ __forceinline__ f32x16 fz16() {
    f32x16 z;
#pragma unroll
    for (int r = 0; r < 16; ++r) z[r] = 0.f;
    return z;
}

// ---------------------------------------------------------------- dtype probe
__global__ void detect_dtype(const unsigned* __restrict__ x, int* __restrict__ flag) {
    int lane = threadIdx.x;
    int cnt = 0;
    for (int i = lane; i < 1024; i += 64) {
        unsigned lo = x[i] & 0xFFFFu;
        unsigned e  = (lo >> 7) & 0xFFu;
        cnt += (e >= 100u && e <= 140u) ? 1 : 0;
    }
    for (int d = 1; d < 64; d <<= 1) cnt += __shfl_xor(cnt, d);
    if (lane == 0) flag[0] = (cnt > 512) ? 1 : 0;  // 1 = bf16 inputs
}

// ---------------------------------------------------------------- bf16 convert
// 8 elems per thread-chunk; grid-stride.
__global__ void convert_bf16(const void* __restrict__ src, unsigned short* __restrict__ dst,
                             int n8, const int* __restrict__ flagp) {
    int i = blockIdx.x * blockDim.x + threadIdx.x;
    int stride = gridDim.x * blockDim.x;
    int fl = *flagp;
    for (; i < n8; i += stride) {
        u32x4 v;
        if (fl) {
            v = *(const u32x4*)((const unsigned short*)src + (long)i * 8);
        } else {
            const float* p = (const float*)src + (long)i * 8;
            f32x4 a = *(const f32x4*)p;
            f32x4 b = *(const f32x4*)(p + 4);
            v[0] = cvt_pk_bf16(a[0], a[1]);
            v[1] = cvt_pk_bf16(a[2], a[3]);
            v[2] = cvt_pk_bf16(b[0], b[1]);
            v[3] = cvt_pk_bf16(b[2], b[3]);
        }
        *(u32x4*)(dst + (long)i * 8) = v;
    }
}

// ---------------------------------------------------------------- GEMM (m97)
// C[M][N] = sum_k A[m][k]*W[n][k]; 128x128 tile, BK=32, linear LDS [128][32],
// staging via global_load_lds width=16 (bf16 operands) or reg-cvt (orig f32).
__device__ __forceinline__ void stage_glds(const unsigned short* __restrict__ src, int ld,
                                           int r0, int k0, unsigned short* lds, int tid) {
#pragma unroll
    for (int h = 0; h < 2; ++h) {
        int c = h * 256 + tid;
        int row = c >> 2, col8 = (c & 3) * 8;
        const unsigned short* gp = src + (r0 + row) * ld + k0 + col8;
        unsigned short* lp = lds + (c & ~63) * 8;   // wave-uniform base; HW adds lane*16B
        __builtin_amdgcn_global_load_lds(
            (const __attribute__((address_space(1))) unsigned short*)gp,
            (__attribute__((address_space(3))) unsigned short*)lp, 16, 0, 0);
    }
}
__device__ __forceinline__ void stage_orig(unsigned short* lds, const void* __restrict__ src,
                                           int ld, int r0, int k0, int fl, int tid) {
    if (fl) { stage_glds((const unsigned short*)src, ld, r0, k0, lds, tid); return; }
#pragma unroll
    for (int h = 0; h < 2; ++h) {
        int c = h * 256 + tid;
        int row = c >> 2, col8 = (c & 3) * 8;
        const float* p = (const float*)src + (long)(r0 + row) * ld + k0 + col8;
        f32x4 a = *(const f32x4*)p;
        f32x4 b = *(const f32x4*)(p + 4);
        u32x4 v;
        v[0] = cvt_pk_bf16(a[0], a[1]);
        v[1] = cvt_pk_bf16(a[2], a[3]);
        v[2] = cvt_pk_bf16(b[0], b[1]);
        v[3] = cvt_pk_bf16(b[2], b[3]);
        *(u32x4*)(lds + row * 32 + col8) = v;
    }
}

template<int OUT_MODE, int A_ORIG, int B_ORIG>
__global__ __launch_bounds__(256, 2)
void gemm2(const void* __restrict__ A, const void* __restrict__ W,
           void* __restrict__ dst, const int* __restrict__ flagp, float scale)
{
    __shared__ unsigned short As[128 * 32];
    __shared__ unsigned short Bs[128 * 32];
    int tid  = threadIdx.x;
    int w    = tid >> 6, lane = tid & 63;
    int wr   = w >> 1,   wc   = w & 1;
    int m0   = blockIdx.y * 128;
    int n0   = blockIdx.x * 128;
    int fl   = *flagp;

    f32x4 zero4 = {0.f, 0.f, 0.f, 0.f};
    f32x4 acc[4][4];
#pragma unroll
    for (int i = 0; i < 4; ++i)
#pragma unroll
        for (int j = 0; j < 4; ++j) acc[i][j] = zero4;

    int lr = lane & 15, lk = (lane >> 4) * 8;

    for (int k0 = 0; k0 < 1024; k0 += 32) {
        __syncthreads();
        if (A_ORIG) stage_orig(As, A, 1024, m0, k0, fl, tid);
        else        stage_glds((const unsigned short*)A, 1024, m0, k0, As, tid);
        if (B_ORIG) stage_orig(Bs, W, 1024, n0, k0, fl, tid);
        else        stage_glds((const unsigned short*)W, 1024, n0, k0, Bs, tid);
        __syncthreads();
        s16x8 af[4], bf[4];
#pragma unroll
        for (int i = 0; i < 4; ++i)
            af[i] = *(const s16x8*)(As + (wr * 64 + i * 16 + lr) * 32 + lk);
#pragma unroll
        for (int j = 0; j < 4; ++j)
            bf[j] = *(const s16x8*)(Bs + (wc * 64 + j * 16 + lr) * 32 + lk);
#pragma unroll
        for (int i = 0; i < 4; ++i)
#pragma unroll
            for (int j = 0; j < 4; ++j)
                acc[i][j] = __builtin_amdgcn_mfma_f32_16x16x32_bf16(af[i], bf[j], acc[i][j], 0, 0, 0);
    }

    int rbase = (lane >> 4) * 4;
#pragma unroll
    for (int i = 0; i < 4; ++i)
#pragma unroll
        for (int j = 0; j < 4; ++j)
#pragma unroll
            for (int r = 0; r < 4; ++r) {
                int m = m0 + wr * 64 + i * 16 + rbase + r;
                int n = n0 + wc * 64 + j * 16 + lr;
                float v = acc[i][j][r] * scale;
                if (OUT_MODE == 0) {
                    int b = m >> 11, s = m & 2047, hh = n >> 6, dk = n & 63;
                    ((unsigned short*)dst)[((((long)b * NH + hh) * NS) + s) * NDK + dk] = f2bf(v);
                } else if (OUT_MODE == 1) {
                    int hh = m >> 6, dk = m & 63, b = n >> 11, s = n & 2047;
                    ((unsigned short*)dst)[((((long)b * NH + hh) * NDK) + dk) * NS + s] = f2bf(v);
                } else {
                    if (fl) ((unsigned short*)dst)[(long)m * 1024 + n] = f2bf(v);
                    else    ((float*)dst)[(long)m * 1024 + n] = v;
                }
            }
}

// ---------------------------------------------------------------- attention v3
// Pair-interleaved swapped-operand flash attention. One 64-thread wave per
// q-tile pair (2i, 2i+1): kv ranges differ by 1 step, so K/V loads and the
// two MFMA chains share an iteration (2x ILP, shared loads). Peeled tail
// handles the two diagonal-masked steps. exp via raw v_exp_f32.
template<bool MASK>
__device__ __forceinline__ void softmax_pf(f32x16& st, float& m, float& l,
                                           f32x16& o0, f32x16& o1,
                                           int kv0, int qb, int l31, int hi,
                                           s16x8& pf0v, s16x8& pf1v)
{
    if (MASK) {
#pragma unroll
        for (int r = 0; r < 16; ++r) {
            int krow = (r & 3) + 8 * (r >> 2) + 4 * hi;
            if (kv0 + krow > qb + l31) st[r] = -1e30f;
        }
    }
    float tm = st[0];
#pragma unroll
    for (int r = 1; r < 16; ++r) tm = fmaxf(tm, st[r]);
    tm = fmaxf(tm, __shfl_xor(tm, 32));
    if (!__all(tm - m <= 8.0f)) {                 // T13 defer-max
        float mn = fmaxf(m, tm);
        float al = exp2_hw((m - mn) * L2E);
        l *= al;
#pragma unroll
        for (int r = 0; r < 16; ++r) { o0[r] *= al; o1[r] *= al; }
        m = mn;
    }
    float ps[16]; float sum = 0.f;
#pragma unroll
    for (int r = 0; r < 16; ++r) {
        ps[r] = exp2_hw((st[r] - m) * L2E);
        sum += ps[r];
    }
    l += sum;
    unsigned b0 = cvt_pk_bf16(ps[0],  ps[1]);
    unsigned b1 = cvt_pk_bf16(ps[2],  ps[3]);
    unsigned b2 = cvt_pk_bf16(ps[4],  ps[5]);
    unsigned b3 = cvt_pk_bf16(ps[6],  ps[7]);
    unsigned b4 = cvt_pk_bf16(ps[8],  ps[9]);
    unsigned b5 = cvt_pk_bf16(ps[10], ps[11]);
    unsigned b6 = cvt_pk_bf16(ps[12], ps[13]);
    unsigned b7 = cvt_pk_bf16(ps[14], ps[15]);
    pl32swap(b0, b2);  pl32swap(b1, b3);
    pl32swap(b4, b6);  pl32swap(b5, b7);
    union { unsigned u[4]; s16x8 v; } pf0, pf1;
    pf0.u[0] = b0; pf0.u[1] = b1; pf0.u[2] = b2; pf0.u[3] = b3;
    pf1.u[0] = b4; pf1.u[1] = b5; pf1.u[2] = b6; pf1.u[3] = b7;
    pf0v = pf0.v; pf1v = pf1.v;
}

template<bool DA, bool DB, bool MA, bool MB>
__device__ __forceinline__ void astep(int kv0, int l31, int hi,
    const unsigned short* __restrict__ Kh, const unsigned short* __restrict__ Vh,
    const s16x8* qfA, const s16x8* qfB,
    f32x16& oA0, f32x16& oA1, f32x16& oB0, f32x16& oB1,
    float& mA, float& lA, float& mB, float& lB, int qbA, int qbB)
{
    s16x8 kf[4];
#pragma unroll
    for (int kd = 0; kd < 4; ++kd)
        kf[kd] = *(const s16x8*)(Kh + (kv0 + l31) * NDK + kd * 16 + hi * 8);
    const unsigned short* v0p = Vh + l31 * NS + kv0 + hi * 8;
    const unsigned short* v1p = v0p + 32 * NS;
    s16x8 va0 = *(const s16x8*)(v0p);
    s16x8 va1 = *(const s16x8*)(v0p + 16);
    s16x8 vb0 = *(const s16x8*)(v1p);
    s16x8 vb1 = *(const s16x8*)(v1p + 16);

    f32x16 stA, stB;
    if (DA) {
        stA = fz16();
#pragma unroll
        for (int kd = 0; kd < 4; ++kd)
            stA = __builtin_amdgcn_mfma_f32_32x32x16_bf16(kf[kd], qfA[kd], stA, 0, 0, 0);
    }
    if (DB) {
        stB = fz16();
#pragma unroll
        for (int kd = 0; kd < 4; ++kd)
            stB = __builtin_amdgcn_mfma_f32_32x32x16_bf16(kf[kd], qfB[kd], stB, 0, 0, 0);
    }
    s16x8 pfA0, pfA1, pfB0, pfB1;
    if (DA) softmax_pf<MA>(stA, mA, lA, oA0, oA1, kv0, qbA, l31, hi, pfA0, pfA1);
    if (DB) softmax_pf<MB>(stB, mB, lB, oB0, oB1, kv0, qbB, l31, hi, pfB0, pfB1);
    if (DA) {
        oA0 = __builtin_amdgcn_mfma_f32_32x32x16_bf16(va0, pfA0, oA0, 0, 0, 0);
        oA0 = __builtin_amdgcn_mfma_f32_32x32x16_bf16(va1, pfA1, oA0, 0, 0, 0);
        oA1 = __builtin_amdgcn_mfma_f32_32x32x16_bf16(vb0, pfA0, oA1, 0, 0, 0);
        oA1 = __builtin_amdgcn_mfma_f32_32x32x16_bf16(vb1, pfA1, oA1, 0, 0, 0);
    }
    if (DB) {
        oB0 = __builtin_amdgcn_mfma_f32_32x32x16_bf16(va0, pfB0, oB0, 0, 0, 0);
        oB0 = __builtin_amdgcn_mfma_f32_32x32x16_bf16(va1, pfB1, oB0, 0, 0, 0);
        oB1 = __builtin_amdgcn_mfma_f32_32x32x16_bf16(vb0, pfB0, oB1, 0, 0, 0);
        oB1 = __builtin_amdgcn_mfma_f32_32x32x16_bf16(vb1, pfB1, oB1, 0, 0, 0);
    }
}

__device__ __forceinline__ void attn_epi(unsigned short* epb, const f32x16& o0, const f32x16& o1,
                                         float lrow, int l31, int hi, int lane,
                                         unsigned short* __restrict__ Oo, int qb, int b, int hh)
{
    float lt = lrow + __shfl_xor(lrow, 32);
    float inv = 1.0f / lt;
#pragma unroll
    for (int j = 0; j < 2; ++j) {
        const f32x16& o = j ? o1 : o0;
#pragma unroll
        for (int g = 0; g < 4; ++g) {
            int d0 = j * 32 + g * 8 + hi * 4;
            unsigned lo = cvt_pk_bf16(o[g * 4 + 0] * inv, o[g * 4 + 1] * inv);
            unsigned hw = cvt_pk_bf16(o[g * 4 + 2] * inv, o[g * 4 + 3] * inv);
            unsigned short* p = epb + l31 * 72 + d0;
            *(unsigned*)(p)     = lo;
            *(unsigned*)(p + 2) = hw;
        }
    }
    asm volatile("s_waitcnt lgkmcnt(0)" ::: "memory");
    __builtin_amdgcn_sched_barrier(0);
#pragma unroll
    for (int rr = 0; rr < 4; ++rr) {
        int q2 = rr * 8 + (lane >> 3);
        int d2 = (lane & 7) * 8;
        u32x4 vv = *(const u32x4*)(epb + q2 * 72 + d2);
        *(u32x4*)(Oo + (((long)b * NS + qb + q2) * ND) + hh * NDK + d2) = vv;
    }
}

__global__ __launch_bounds__(64, 2)
void attn_fwd3(const unsigned short* __restrict__ Q,
               const unsigned short* __restrict__ Kt,
               const unsigned short* __restrict__ Vt,
               unsigned short* __restrict__ Oo,
               const int* __restrict__ causalp)
{
    __shared__ unsigned short ep[2][32 * 72];
    int lane = threadIdx.x;
    int l31 = lane & 31, hi = lane >> 5;
    int bh  = blockIdx.y;
    int i   = blockIdx.x;                 // pair index 0..31
    int qbA = i * 64, qbB = i * 64 + 32;
    int LA  = 2 * i + 1;                  // kv-steps for tile A
    int causal = *causalp;

    const unsigned short* Qh = Q  + bh * (NS * NDK);
    const unsigned short* Kh = Kt + bh * (NS * NDK);
    const unsigned short* Vh = Vt + bh * (NDK * NS);

    s16x8 qfA[4], qfB[4];
#pragma unroll
    for (int kd = 0; kd < 4; ++kd) {
        qfA[kd] = *(const s16x8*)(Qh + (qbA + l31) * NDK + kd * 16 + hi * 8);
        qfB[kd] = *(const s16x8*)(Qh + (qbB + l31) * NDK + kd * 16 + hi * 8);
    }

    f32x16 oA0 = fz16(), oA1 = fz16(), oB0 = fz16(), oB1 = fz16();
    float mA = -1e30f, lA = 0.f, mB = -1e30f, lB = 0.f;

    if (causal) {
        int kv0 = 0;
        for (int it = 0; it < LA - 1; ++it, kv0 += 32)
            astep<true, true, false, false>(kv0, l31, hi, Kh, Vh, qfA, qfB,
                oA0, oA1, oB0, oB1, mA, lA, mB, lB, qbA, qbB);
        astep<true, true, true, false>(kv0, l31, hi, Kh, Vh, qfA, qfB,
            oA0, oA1, oB0, oB1, mA, lA, mB, lB, qbA, qbB);
        kv0 += 32;
        astep<false, true, false, true>(kv0, l31, hi, Kh, Vh, qfA, qfB,
            oA0, oA1, oB0, oB1, mA, lA, mB, lB, qbA, qbB);
    } else {
        for (int kv0 = 0; kv0 < NS; kv0 += 32)
            astep<true, true, false, false>(kv0, l31, hi, Kh, Vh, qfA, qfB,
                oA0, oA1, oB0, oB1, mA, lA, mB, lB, qbA, qbB);
    }

    int b = bh >> 4, hh = bh & 15;
    attn_epi(&ep[0][0], oA0, oA1, lA, l31, hi, lane, Oo, qbA, b, hh);
    attn_epi(&ep[1][0], oB0, oB1, lB, l31, hi, lane, Oo, qbB, b, hh);
}

// ---------------------------------------------------------------- launch
extern "C" void kernel_launch(void* const* d_in, const int* in_sizes, int n_in,
                              void* d_out, int out_size, void* d_ws, size_t ws_size,
                              hipStream_t stream) {
    const void* x  = d_in[0];
    const void* Wq = d_in[1];
    const void* Wk = d_in[2];
    const void* Wv = d_in[3];
    const void* Wo = d_in[4];
    const int* causal = (const int*)d_in[5];

    const long TOK  = (long)NB * NS * ND;   // 8.39M elems
    const long WTOK = (long)ND * ND;        // 1.05M elems
    size_t need = 256 + 4UL * TOK * 2;      // same 67.1MB footprint as before
    if (ws_size < need) return;

    char* ws = (char*)d_ws;
    int* flag = (int*)ws;
    unsigned short* Qb = (unsigned short*)(ws + 256);
    unsigned short* Kb = Qb + TOK;
    unsigned short* Vb = Kb + TOK;
    unsigned short* XB = Vb + TOK;          // x_bf16; later reused as attn out Ab
    unsigned short* Ab = XB;
    unsigned short* WS1 = Kb + TOK - WTOK;  // dead tail of Kb until K-GEMM writes
    unsigned short* WS2 = Vb + TOK - WTOK;  // dead tail of Vb until V-GEMM writes

    detect_dtype<<<1, 64, 0, stream>>>((const unsigned*)x, flag);

    // pre-convert x and W_Q/W_K to bf16
    convert_bf16<<<2048, 256, 0, stream>>>(x,  XB,  (int)(TOK / 8),  flag);
    convert_bf16<<<512,  256, 0, stream>>>(Wq, WS1, (int)(WTOK / 8), flag);
    convert_bf16<<<512,  256, 0, stream>>>(Wk, WS2, (int)(WTOK / 8), flag);

    dim3 blk(256);
    // Q = x·Wq^T (scaled 1/8), K = x·Wk^T
    gemm2<0, 0, 0><<<dim3(8, 64), blk, 0, stream>>>(XB, WS1, Qb, flag, 0.125f);
    gemm2<0, 0, 0><<<dim3(8, 64), blk, 0, stream>>>(XB, WS2, Kb, flag, 1.0f);
    // V^T: swapped operands, A = Wv (orig dtype, reg-staged), B = x_bf16
    gemm2<1, 1, 0><<<dim3(64, 8), blk, 0, stream>>>(Wv, XB, Vb, flag, 1.0f);
    // attention (writes Ab == XB region; x no longer needed)
    attn_fwd3<<<dim3(32, 64), 64, 0, stream>>>(Qb, Kb, Vb, Ab, causal);
    // out = attn·Wo^T, B = Wo (orig dtype, reg-staged)
    gemm2<2, 0, 1><<<dim3(8, 64), blk, 0, stream>>>(Ab, Wo, d_out, flag, 1.0f);
}

// Round 4
// 277.819 us; speedup vs baseline: 2.6019x; 1.0111x over previous
//
#include <hip/hip_runtime.h>
#include <stdint.h>

#define NB 4
#define NS 2048
#define ND 1024
#define NH 16
#define NDK 64
#define L2E 1.44269504088896340736f

typedef __attribute__((ext_vector_type(8)))  short     s16x8;
typedef __attribute__((ext_vector_type(4)))  float     f32x4;
typedef __attribute__((ext_vector_type(16))) float     f32x16;
typedef __attribute__((ext_vector_type(4)))  unsigned  u32x4;

__device__ __forceinline__ unsigned short f2bf(float f) {
    union { float f; unsigned u; } v; v.f = f;
    unsigned r = v.u + 0x7FFFu + ((v.u >> 16) & 1u);
    return (unsigned short)(r >> 16);
}
__device__ __forceinline__ unsigned cvt_pk_bf16(float lo, float hi) {
    unsigned r;
    asm("v_cvt_pk_bf16_f32 %0, %1, %2" : "=v"(r) : "v"(lo), "v"(hi));
    return r;
}
__device__ __forceinline__ void pl32swap(unsigned &a, unsigned &b) {
    asm volatile("v_permlane32_swap_b32 %0, %1" : "+v"(a), "+v"(b));
}
__device__ __forceinline__ float exp2_hw(float x) {
    float r; asm("v_exp_f32 %0, %1" : "=v"(r) : "v"(x)); return r;
}
__device__ __forceinline__ f32x16 fz16() {
    f32x16 z;
#pragma unroll
    for (int r = 0; r < 16; ++r) z[r] = 0.f;
    return z;
}

// ---------------------------------------------------------------- dtype probe
__global__ void detect_dtype(const unsigned* __restrict__ x, int* __restrict__ flag) {
    int lane = threadIdx.x;
    int cnt = 0;
    for (int i = lane; i < 1024; i += 64) {
        unsigned lo = x[i] & 0xFFFFu;
        unsigned e  = (lo >> 7) & 0xFFu;
        cnt += (e >= 100u && e <= 140u) ? 1 : 0;
    }
    for (int d = 1; d < 64; d <<= 1) cnt += __shfl_xor(cnt, d);
    if (lane == 0) flag[0] = (cnt > 512) ? 1 : 0;  // 1 = bf16 inputs
}

// ---------------------------------------------------------------- bf16 convert
__global__ void convert_bf16(const void* __restrict__ src, unsigned short* __restrict__ dst,
                             int n8, const int* __restrict__ flagp) {
    int i = blockIdx.x * blockDim.x + threadIdx.x;
    int stride = gridDim.x * blockDim.x;
    int fl = *flagp;
    for (; i < n8; i += stride) {
        u32x4 v;
        if (fl) {
            v = *(const u32x4*)((const unsigned short*)src + (long)i * 8);
        } else {
            const float* p = (const float*)src + (long)i * 8;
            f32x4 a = *(const f32x4*)p;
            f32x4 b = *(const f32x4*)(p + 4);
            v[0] = cvt_pk_bf16(a[0], a[1]);
            v[1] = cvt_pk_bf16(a[2], a[3]);
            v[2] = cvt_pk_bf16(b[0], b[1]);
            v[3] = cvt_pk_bf16(b[2], b[3]);
        }
        *(u32x4*)(dst + (long)i * 8) = v;
    }
}

// ---------------------------------------------------------------- GEMM (m97)
__device__ __forceinline__ void stage_glds(const unsigned short* __restrict__ src, int ld,
                                           int r0, int k0, unsigned short* lds, int tid) {
#pragma unroll
    for (int h = 0; h < 2; ++h) {
        int c = h * 256 + tid;
        int row = c >> 2, col8 = (c & 3) * 8;
        const unsigned short* gp = src + (r0 + row) * ld + k0 + col8;
        unsigned short* lp = lds + (c & ~63) * 8;
        __builtin_amdgcn_global_load_lds(
            (const __attribute__((address_space(1))) unsigned short*)gp,
            (__attribute__((address_space(3))) unsigned short*)lp, 16, 0, 0);
    }
}
__device__ __forceinline__ void stage_orig(unsigned short* lds, const void* __restrict__ src,
                                           int ld, int r0, int k0, int fl, int tid) {
    if (fl) { stage_glds((const unsigned short*)src, ld, r0, k0, lds, tid); return; }
#pragma unroll
    for (int h = 0; h < 2; ++h) {
        int c = h * 256 + tid;
        int row = c >> 2, col8 = (c & 3) * 8;
        const float* p = (const float*)src + (long)(r0 + row) * ld + k0 + col8;
        f32x4 a = *(const f32x4*)p;
        f32x4 b = *(const f32x4*)(p + 4);
        u32x4 v;
        v[0] = cvt_pk_bf16(a[0], a[1]);
        v[1] = cvt_pk_bf16(a[2], a[3]);
        v[2] = cvt_pk_bf16(b[0], b[1]);
        v[3] = cvt_pk_bf16(b[2], b[3]);
        *(u32x4*)(lds + row * 32 + col8) = v;
    }
}

template<int OUT_MODE, int A_ORIG, int B_ORIG>
__global__ __launch_bounds__(256, 2)
void gemm2(const void* __restrict__ A, const void* __restrict__ W,
           void* __restrict__ dst, const int* __restrict__ flagp, float scale)
{
    __shared__ unsigned short As[128 * 32];
    __shared__ unsigned short Bs[128 * 32];
    int tid  = threadIdx.x;
    int w    = tid >> 6, lane = tid & 63;
    int wr   = w >> 1,   wc   = w & 1;
    int m0   = blockIdx.y * 128;
    int n0   = blockIdx.x * 128;
    int fl   = *flagp;

    f32x4 zero4 = {0.f, 0.f, 0.f, 0.f};
    f32x4 acc[4][4];
#pragma unroll
    for (int i = 0; i < 4; ++i)
#pragma unroll
        for (int j = 0; j < 4; ++j) acc[i][j] = zero4;

    int lr = lane & 15, lk = (lane >> 4) * 8;

    for (int k0 = 0; k0 < 1024; k0 += 32) {
        __syncthreads();
        if (A_ORIG) stage_orig(As, A, 1024, m0, k0, fl, tid);
        else        stage_glds((const unsigned short*)A, 1024, m0, k0, As, tid);
        if (B_ORIG) stage_orig(Bs, W, 1024, n0, k0, fl, tid);
        else        stage_glds((const unsigned short*)W, 1024, n0, k0, Bs, tid);
        __syncthreads();
        s16x8 af[4], bf[4];
#pragma unroll
        for (int i = 0; i < 4; ++i)
            af[i] = *(const s16x8*)(As + (wr * 64 + i * 16 + lr) * 32 + lk);
#pragma unroll
        for (int j = 0; j < 4; ++j)
            bf[j] = *(const s16x8*)(Bs + (wc * 64 + j * 16 + lr) * 32 + lk);
#pragma unroll
        for (int i = 0; i < 4; ++i)
#pragma unroll
            for (int j = 0; j < 4; ++j)
                acc[i][j] = __builtin_amdgcn_mfma_f32_16x16x32_bf16(af[i], bf[j], acc[i][j], 0, 0, 0);
    }

    int rbase = (lane >> 4) * 4;
#pragma unroll
    for (int i = 0; i < 4; ++i)
#pragma unroll
        for (int j = 0; j < 4; ++j)
#pragma unroll
            for (int r = 0; r < 4; ++r) {
                int m = m0 + wr * 64 + i * 16 + rbase + r;
                int n = n0 + wc * 64 + j * 16 + lr;
                float v = acc[i][j][r] * scale;
                if (OUT_MODE == 0) {
                    int b = m >> 11, s = m & 2047, hh = n >> 6, dk = n & 63;
                    ((unsigned short*)dst)[((((long)b * NH + hh) * NS) + s) * NDK + dk] = f2bf(v);
                } else if (OUT_MODE == 1) {
                    int hh = m >> 6, dk = m & 63, b = n >> 11, s = n & 2047;
                    ((unsigned short*)dst)[((((long)b * NH + hh) * NDK) + dk) * NS + s] = f2bf(v);
                } else {
                    if (fl) ((unsigned short*)dst)[(long)m * 1024 + n] = f2bf(v);
                    else    ((float*)dst)[(long)m * 1024 + n] = v;
                }
            }
}

// ---------------------------------------------------------------- attention v4
// 4-wave blocks: block (j, bh); wave w owns q-tile t=4j+w (32 rows).
// K tile (32kv x 64dk, 4KB contiguous) staged via global_load_lds into
// double-buffered LDS, XOR-swizzled on the SOURCE side (linear dest) so the
// ds_read_b128 fragment reads are ~4-way instead of 32-way conflicted.
// V^T read per-lane from global: identical addresses across the 4 waves (L1
// broadcast), independent of QK^T so latency hides under compute.
// Softmax in log2 domain (Q pre-scaled by 0.125*L2E at projection).
__device__ __forceinline__ void stage_K(const unsigned short* __restrict__ Kh, int kv0,
                                        unsigned short* kb, int tid) {
    int L   = tid * 16;                             // linear LDS byte offset
    int src = L ^ (((tid >> 3) & 7) << 4);          // involution swizzle on source
    const unsigned short* gp = (const unsigned short*)((const char*)(Kh + kv0 * NDK) + src);
    unsigned short* lp = kb + (tid & ~63) * 8;      // wave-uniform base; HW adds lane*16B
    __builtin_amdgcn_global_load_lds(
        (const __attribute__((address_space(1))) unsigned short*)gp,
        (__attribute__((address_space(3))) unsigned short*)lp, 16, 0, 0);
}

template<bool MASK>
__device__ __forceinline__ void sm_step(f32x16& st, float& m, float& l,
                                        f32x16& o0, f32x16& o1,
                                        int kv0, int qb, int l31, int hi,
                                        s16x8& pf0v, s16x8& pf1v)
{
    if (MASK) {
#pragma unroll
        for (int r = 0; r < 16; ++r) {
            int krow = (r & 3) + 8 * (r >> 2) + 4 * hi;
            if (kv0 + krow > qb + l31) st[r] = -1e30f;
        }
    }
    float tm = st[0];
#pragma unroll
    for (int r = 1; r < 16; ++r) tm = fmaxf(tm, st[r]);
    tm = fmaxf(tm, __shfl_xor(tm, 32));
    if (!__all(tm - m <= 8.0f)) {                 // defer-max (log2 units)
        float mn = fmaxf(m, tm);
        float al = exp2_hw(m - mn);
        l *= al;
#pragma unroll
        for (int r = 0; r < 16; ++r) { o0[r] *= al; o1[r] *= al; }
        m = mn;
    }
    float ps[16]; float sum = 0.f;
#pragma unroll
    for (int r = 0; r < 16; ++r) {
        ps[r] = exp2_hw(st[r] - m);               // st already log2-scaled
        sum += ps[r];
    }
    l += sum;
    unsigned b0 = cvt_pk_bf16(ps[0],  ps[1]);
    unsigned b1 = cvt_pk_bf16(ps[2],  ps[3]);
    unsigned b2 = cvt_pk_bf16(ps[4],  ps[5]);
    unsigned b3 = cvt_pk_bf16(ps[6],  ps[7]);
    unsigned b4 = cvt_pk_bf16(ps[8],  ps[9]);
    unsigned b5 = cvt_pk_bf16(ps[10], ps[11]);
    unsigned b6 = cvt_pk_bf16(ps[12], ps[13]);
    unsigned b7 = cvt_pk_bf16(ps[14], ps[15]);
    pl32swap(b0, b2);  pl32swap(b1, b3);
    pl32swap(b4, b6);  pl32swap(b5, b7);
    union { unsigned u[4]; s16x8 v; } pf0, pf1;
    pf0.u[0] = b0; pf0.u[1] = b1; pf0.u[2] = b2; pf0.u[3] = b3;
    pf1.u[0] = b4; pf1.u[1] = b5; pf1.u[2] = b6; pf1.u[3] = b7;
    pf0v = pf0.v; pf1v = pf1.v;
}

template<bool MASK>
__device__ __forceinline__ void astep4(const unsigned short* kb, const int* koff,
                                       const unsigned short* vbase, int kv0,
                                       const s16x8* qf,
                                       f32x16& o0, f32x16& o1, float& m, float& l,
                                       int qb, int l31, int hi)
{
    s16x8 kf[4];
#pragma unroll
    for (int kd = 0; kd < 4; ++kd)
        kf[kd] = *(const s16x8*)(kb + koff[kd]);
    s16x8 va0 = *(const s16x8*)(vbase + kv0);
    s16x8 va1 = *(const s16x8*)(vbase + kv0 + 16);
    s16x8 vb0 = *(const s16x8*)(vbase + 32 * NS + kv0);
    s16x8 vb1 = *(const s16x8*)(vbase + 32 * NS + kv0 + 16);

    f32x16 st = fz16();
#pragma unroll
    for (int kd = 0; kd < 4; ++kd)
        st = __builtin_amdgcn_mfma_f32_32x32x16_bf16(kf[kd], qf[kd], st, 0, 0, 0);

    s16x8 pf0, pf1;
    sm_step<MASK>(st, m, l, o0, o1, kv0, qb, l31, hi, pf0, pf1);

    o0 = __builtin_amdgcn_mfma_f32_32x32x16_bf16(va0, pf0, o0, 0, 0, 0);
    o0 = __builtin_amdgcn_mfma_f32_32x32x16_bf16(va1, pf1, o0, 0, 0, 0);
    o1 = __builtin_amdgcn_mfma_f32_32x32x16_bf16(vb0, pf0, o1, 0, 0, 0);
    o1 = __builtin_amdgcn_mfma_f32_32x32x16_bf16(vb1, pf1, o1, 0, 0, 0);
}

__device__ __forceinline__ void attn_epi(unsigned short* epb, const f32x16& o0, const f32x16& o1,
                                         float lrow, int l31, int hi, int lane,
                                         unsigned short* __restrict__ Oo, int qb, int b, int hh)
{
    float lt = lrow + __shfl_xor(lrow, 32);
    float inv = 1.0f / lt;
#pragma unroll
    for (int j = 0; j < 2; ++j) {
        const f32x16& o = j ? o1 : o0;
#pragma unroll
        for (int g = 0; g < 4; ++g) {
            int d0 = j * 32 + g * 8 + hi * 4;
            unsigned lo = cvt_pk_bf16(o[g * 4 + 0] * inv, o[g * 4 + 1] * inv);
            unsigned hw = cvt_pk_bf16(o[g * 4 + 2] * inv, o[g * 4 + 3] * inv);
            unsigned short* p = epb + l31 * 72 + d0;
            *(unsigned*)(p)     = lo;
            *(unsigned*)(p + 2) = hw;
        }
    }
    asm volatile("s_waitcnt lgkmcnt(0)" ::: "memory");
    __builtin_amdgcn_sched_barrier(0);
#pragma unroll
    for (int rr = 0; rr < 4; ++rr) {
        int q2 = rr * 8 + (lane >> 3);
        int d2 = (lane & 7) * 8;
        u32x4 vv = *(const u32x4*)(epb + q2 * 72 + d2);
        *(u32x4*)(Oo + (((long)b * NS + qb + q2) * ND) + hh * NDK + d2) = vv;
    }
}

__global__ __launch_bounds__(256, 2)
void attn_fwd4(const unsigned short* __restrict__ Q,
               const unsigned short* __restrict__ Kt,
               const unsigned short* __restrict__ Vt,
               unsigned short* __restrict__ Oo,
               const int* __restrict__ causalp)
{
    __shared__ unsigned short Kb[2][32 * 64];
    __shared__ unsigned short ep[4][32 * 72];
    int tid = threadIdx.x, w = tid >> 6, lane = tid & 63;
    int l31 = lane & 31, hi = lane >> 5;
    int j = blockIdx.x, bh = blockIdx.y;
    int t = 4 * j + w, qb = t * 32;
    int causal = *causalp;
    int Nst = causal ? (4 * j + 4) : (NS / 32);

    const unsigned short* Qh = Q  + bh * (NS * NDK);
    const unsigned short* Kh = Kt + bh * (NS * NDK);
    const unsigned short* Vh = Vt + bh * (NDK * NS);
    const unsigned short* vbase = Vh + l31 * NS + hi * 8;

    s16x8 qf[4];
#pragma unroll
    for (int kd = 0; kd < 4; ++kd)
        qf[kd] = *(const s16x8*)(Qh + (qb + l31) * NDK + kd * 16 + hi * 8);

    int sw = (l31 & 7) << 4;
    int koff[4];
#pragma unroll
    for (int kd = 0; kd < 4; ++kd)
        koff[kd] = l31 * 64 + (((kd * 32 + hi * 16) ^ sw) >> 1);

    f32x16 o0 = fz16(), o1 = fz16();
    float m = -1e30f, l = 0.f;

    stage_K(Kh, 0, Kb[0], tid);
    __syncthreads();

    for (int s = 0; s < Nst; ++s) {
        int cur = s & 1;
        if (s + 1 < Nst) stage_K(Kh, (s + 1) * 32, Kb[cur ^ 1], tid);
        const unsigned short* kb = Kb[cur];
        if (!causal || s < t)
            astep4<false>(kb, koff, vbase, s * 32, qf, o0, o1, m, l, qb, l31, hi);
        else if (s == t)
            astep4<true>(kb, koff, vbase, s * 32, qf, o0, o1, m, l, qb, l31, hi);
        __syncthreads();
    }

    attn_epi(&ep[w][0], o0, o1, l, l31, hi, lane, Oo, qb, bh >> 4, bh & 15);
}

// ---------------------------------------------------------------- launch
extern "C" void kernel_launch(void* const* d_in, const int* in_sizes, int n_in,
                              void* d_out, int out_size, void* d_ws, size_t ws_size,
                              hipStream_t stream) {
    const void* x  = d_in[0];
    const void* Wq = d_in[1];
    const void* Wk = d_in[2];
    const void* Wv = d_in[3];
    const void* Wo = d_in[4];
    const int* causal = (const int*)d_in[5];

    const long TOK  = (long)NB * NS * ND;
    const long WTOK = (long)ND * ND;
    size_t need = 256 + 4UL * TOK * 2;
    if (ws_size < need) return;

    char* ws = (char*)d_ws;
    int* flag = (int*)ws;
    unsigned short* Qb = (unsigned short*)(ws + 256);
    unsigned short* Kb = Qb + TOK;
    unsigned short* Vb = Kb + TOK;
    unsigned short* XB = Vb + TOK;          // x_bf16; later reused as attn out Ab
    unsigned short* Ab = XB;
    unsigned short* WS1 = Kb + TOK - WTOK;  // dead tail of Kb until K-GEMM writes
    unsigned short* WS2 = Vb + TOK - WTOK;  // dead tail of Vb until V-GEMM writes

    detect_dtype<<<1, 64, 0, stream>>>((const unsigned*)x, flag);

    convert_bf16<<<2048, 256, 0, stream>>>(x,  XB,  (int)(TOK / 8),  flag);
    convert_bf16<<<512,  256, 0, stream>>>(Wq, WS1, (int)(WTOK / 8), flag);
    convert_bf16<<<512,  256, 0, stream>>>(Wk, WS2, (int)(WTOK / 8), flag);

    dim3 blk(256);
    // Q = x·Wq^T, scaled 0.125*log2(e) so softmax runs in log2 domain
    gemm2<0, 0, 0><<<dim3(8, 64), blk, 0, stream>>>(XB, WS1, Qb, flag, 0.125f * L2E);
    gemm2<0, 0, 0><<<dim3(8, 64), blk, 0, stream>>>(XB, WS2, Kb, flag, 1.0f);
    gemm2<1, 1, 0><<<dim3(64, 8), blk, 0, stream>>>(Wv, XB, Vb, flag, 1.0f);
    attn_fwd4<<<dim3(16, 64), blk, 0, stream>>>(Qb, Kb, Vb, Ab, causal);
    gemm2<2, 0, 1><<<dim3(8, 64), blk, 0, stream>>>(Ab, Wo, d_out, flag, 1.0f);
}

// Round 5
// 264.024 us; speedup vs baseline: 2.7379x; 1.0522x over previous
//
#include <hip/hip_runtime.h>
#include <stdint.h>

#define NB 4
#define NS 2048
#define ND 1024
#define NH 16
#define NDK 64
#define L2E 1.44269504088896340736f

typedef __attribute__((ext_vector_type(8)))  short     s16x8;
typedef __attribute__((ext_vector_type(4)))  float     f32x4;
typedef __attribute__((ext_vector_type(16))) float     f32x16;
typedef __attribute__((ext_vector_type(4)))  unsigned  u32x4;

__device__ __forceinline__ unsigned short f2bf(float f) {
    union { float f; unsigned u; } v; v.f = f;
    unsigned r = v.u + 0x7FFFu + ((v.u >> 16) & 1u);
    return (unsigned short)(r >> 16);
}
__device__ __forceinline__ unsigned cvt_pk_bf16(float lo, float hi) {
    unsigned r;
    asm("v_cvt_pk_bf16_f32 %0, %1, %2" : "=v"(r) : "v"(lo), "v"(hi));
    return r;
}
__device__ __forceinline__ void pl32swap(unsigned &a, unsigned &b) {
    asm volatile("v_permlane32_swap_b32 %0, %1" : "+v"(a), "+v"(b));
}
__device__ __forceinline__ float exp2_hw(float x) {
    float r; asm("v_exp_f32 %0, %1" : "=v"(r) : "v"(x)); return r;
}
__device__ __forceinline__ f32x16 fz16() {
    f32x16 z;
#pragma unroll
    for (int r = 0; r < 16; ++r) z[r] = 0.f;
    return z;
}
__device__ __forceinline__ f32x16 mfma32(const s16x8& a, const s16x8& b, const f32x16& c) {
    return __builtin_amdgcn_mfma_f32_32x32x16_bf16(a, b, c, 0, 0, 0);
}

// ---------------------------------------------------------------- dtype probe
__global__ void detect_dtype(const unsigned* __restrict__ x, int* __restrict__ flag) {
    int lane = threadIdx.x;
    int cnt = 0;
    for (int i = lane; i < 1024; i += 64) {
        unsigned lo = x[i] & 0xFFFFu;
        unsigned e  = (lo >> 7) & 0xFFu;
        cnt += (e >= 100u && e <= 140u) ? 1 : 0;
    }
    for (int d = 1; d < 64; d <<= 1) cnt += __shfl_xor(cnt, d);
    if (lane == 0) flag[0] = (cnt > 512) ? 1 : 0;  // 1 = bf16 inputs
}

// ---------------------------------------------------------------- bf16 convert
__global__ void convert_bf16(const void* __restrict__ src, unsigned short* __restrict__ dst,
                             int n8, const int* __restrict__ flagp) {
    int i = blockIdx.x * blockDim.x + threadIdx.x;
    int stride = gridDim.x * blockDim.x;
    int fl = *flagp;
    for (; i < n8; i += stride) {
        u32x4 v;
        if (fl) {
            v = *(const u32x4*)((const unsigned short*)src + (long)i * 8);
        } else {
            const float* p = (const float*)src + (long)i * 8;
            f32x4 a = *(const f32x4*)p;
            f32x4 b = *(const f32x4*)(p + 4);
            v[0] = cvt_pk_bf16(a[0], a[1]);
            v[1] = cvt_pk_bf16(a[2], a[3]);
            v[2] = cvt_pk_bf16(b[0], b[1]);
            v[3] = cvt_pk_bf16(b[2], b[3]);
        }
        *(u32x4*)(dst + (long)i * 8) = v;
    }
}

// ---------------------------------------------------------------- GEMM (m97)
__device__ __forceinline__ void stage_glds(const unsigned short* __restrict__ src, int ld,
                                           int r0, int k0, unsigned short* lds, int tid) {
#pragma unroll
    for (int h = 0; h < 2; ++h) {
        int c = h * 256 + tid;
        int row = c >> 2, col8 = (c & 3) * 8;
        const unsigned short* gp = src + (r0 + row) * ld + k0 + col8;
        unsigned short* lp = lds + (c & ~63) * 8;
        __builtin_amdgcn_global_load_lds(
            (const __attribute__((address_space(1))) unsigned short*)gp,
            (__attribute__((address_space(3))) unsigned short*)lp, 16, 0, 0);
    }
}
__device__ __forceinline__ void stage_orig(unsigned short* lds, const void* __restrict__ src,
                                           int ld, int r0, int k0, int fl, int tid) {
    if (fl) { stage_glds((const unsigned short*)src, ld, r0, k0, lds, tid); return; }
#pragma unroll
    for (int h = 0; h < 2; ++h) {
        int c = h * 256 + tid;
        int row = c >> 2, col8 = (c & 3) * 8;
        const float* p = (const float*)src + (long)(r0 + row) * ld + k0 + col8;
        f32x4 a = *(const f32x4*)p;
        f32x4 b = *(const f32x4*)(p + 4);
        u32x4 v;
        v[0] = cvt_pk_bf16(a[0], a[1]);
        v[1] = cvt_pk_bf16(a[2], a[3]);
        v[2] = cvt_pk_bf16(b[0], b[1]);
        v[3] = cvt_pk_bf16(b[2], b[3]);
        *(u32x4*)(lds + row * 32 + col8) = v;
    }
}

template<int OUT_MODE, int A_ORIG, int B_ORIG>
__global__ __launch_bounds__(256, 2)
void gemm2(const void* __restrict__ A, const void* __restrict__ W,
           void* __restrict__ dst, const int* __restrict__ flagp, float scale)
{
    __shared__ unsigned short As[128 * 32];
    __shared__ unsigned short Bs[128 * 32];
    int tid  = threadIdx.x;
    int w    = tid >> 6, lane = tid & 63;
    int wr   = w >> 1,   wc   = w & 1;
    int m0   = blockIdx.y * 128;
    int n0   = blockIdx.x * 128;
    int fl   = *flagp;

    f32x4 zero4 = {0.f, 0.f, 0.f, 0.f};
    f32x4 acc[4][4];
#pragma unroll
    for (int i = 0; i < 4; ++i)
#pragma unroll
        for (int j = 0; j < 4; ++j) acc[i][j] = zero4;

    int lr = lane & 15, lk = (lane >> 4) * 8;

    for (int k0 = 0; k0 < 1024; k0 += 32) {
        __syncthreads();
        if (A_ORIG) stage_orig(As, A, 1024, m0, k0, fl, tid);
        else        stage_glds((const unsigned short*)A, 1024, m0, k0, As, tid);
        if (B_ORIG) stage_orig(Bs, W, 1024, n0, k0, fl, tid);
        else        stage_glds((const unsigned short*)W, 1024, n0, k0, Bs, tid);
        __syncthreads();
        s16x8 af[4], bf[4];
#pragma unroll
        for (int i = 0; i < 4; ++i)
            af[i] = *(const s16x8*)(As + (wr * 64 + i * 16 + lr) * 32 + lk);
#pragma unroll
        for (int j = 0; j < 4; ++j)
            bf[j] = *(const s16x8*)(Bs + (wc * 64 + j * 16 + lr) * 32 + lk);
#pragma unroll
        for (int i = 0; i < 4; ++i)
#pragma unroll
            for (int j = 0; j < 4; ++j)
                acc[i][j] = __builtin_amdgcn_mfma_f32_16x16x32_bf16(af[i], bf[j], acc[i][j], 0, 0, 0);
    }

    int rbase = (lane >> 4) * 4;
#pragma unroll
    for (int i = 0; i < 4; ++i)
#pragma unroll
        for (int j = 0; j < 4; ++j)
#pragma unroll
            for (int r = 0; r < 4; ++r) {
                int m = m0 + wr * 64 + i * 16 + rbase + r;
                int n = n0 + wc * 64 + j * 16 + lr;
                float v = acc[i][j][r] * scale;
                if (OUT_MODE == 0) {
                    int b = m >> 11, s = m & 2047, hh = n >> 6, dk = n & 63;
                    ((unsigned short*)dst)[((((long)b * NH + hh) * NS) + s) * NDK + dk] = f2bf(v);
                } else if (OUT_MODE == 1) {
                    int hh = m >> 6, dk = m & 63, b = n >> 11, s = n & 2047;
                    ((unsigned short*)dst)[((((long)b * NH + hh) * NDK) + dk) * NS + s] = f2bf(v);
                } else {
                    if (fl) ((unsigned short*)dst)[(long)m * 1024 + n] = f2bf(v);
                    else    ((float*)dst)[(long)m * 1024 + n] = v;
                }
            }
}

// ---------------------------------------------------------------- attention v5
// Independent waves (no block barriers). Wave i (global pair index 0..31)
// owns q-tiles A=i and B=63-i: (i+1)+(64-i)=65 step-units for EVERY wave
// (uniform duration). K/V register double-buffer: step s+1's loads issue
// before step s's compute (latency hidden under 8-16 MFMA + softmax).
// Softmax in log2 domain (Q pre-scaled by 0.125*log2e at projection).
__device__ __forceinline__ void loadKV(const unsigned short* __restrict__ Kh,
                                       const unsigned short* __restrict__ vbase,
                                       int kv0, s16x8* kf, s16x8* vf, int l31, int hi) {
#pragma unroll
    for (int kd = 0; kd < 4; ++kd)
        kf[kd] = *(const s16x8*)(Kh + (kv0 + l31) * NDK + kd * 16 + hi * 8);
    vf[0] = *(const s16x8*)(vbase + kv0);
    vf[1] = *(const s16x8*)(vbase + kv0 + 16);
    vf[2] = *(const s16x8*)(vbase + 32 * NS + kv0);
    vf[3] = *(const s16x8*)(vbase + 32 * NS + kv0 + 16);
}

__device__ __forceinline__ void sm_step(f32x16& st, float& m, float& l,
                                        f32x16& o0, f32x16& o1,
                                        bool mask, int kv0, int qb, int l31, int hi,
                                        s16x8& pf0v, s16x8& pf1v)
{
    if (mask) {
#pragma unroll
        for (int r = 0; r < 16; ++r) {
            int krow = (r & 3) + 8 * (r >> 2) + 4 * hi;
            if (kv0 + krow > qb + l31) st[r] = -1e30f;
        }
    }
    float tm = st[0];
#pragma unroll
    for (int r = 1; r < 16; ++r) tm = fmaxf(tm, st[r]);
    tm = fmaxf(tm, __shfl_xor(tm, 32));
    if (!__all(tm - m <= 8.0f)) {                 // defer-max (log2 units)
        float mn = fmaxf(m, tm);
        float al = exp2_hw(m - mn);
        l *= al;
#pragma unroll
        for (int r = 0; r < 16; ++r) { o0[r] *= al; o1[r] *= al; }
        m = mn;
    }
    float ps[16]; float sum = 0.f;
#pragma unroll
    for (int r = 0; r < 16; ++r) {
        ps[r] = exp2_hw(st[r] - m);
        sum += ps[r];
    }
    l += sum;
    unsigned b0 = cvt_pk_bf16(ps[0],  ps[1]);
    unsigned b1 = cvt_pk_bf16(ps[2],  ps[3]);
    unsigned b2 = cvt_pk_bf16(ps[4],  ps[5]);
    unsigned b3 = cvt_pk_bf16(ps[6],  ps[7]);
    unsigned b4 = cvt_pk_bf16(ps[8],  ps[9]);
    unsigned b5 = cvt_pk_bf16(ps[10], ps[11]);
    unsigned b6 = cvt_pk_bf16(ps[12], ps[13]);
    unsigned b7 = cvt_pk_bf16(ps[14], ps[15]);
    pl32swap(b0, b2);  pl32swap(b1, b3);
    pl32swap(b4, b6);  pl32swap(b5, b7);
    union { unsigned u[4]; s16x8 v; } pf0, pf1;
    pf0.u[0] = b0; pf0.u[1] = b1; pf0.u[2] = b2; pf0.u[3] = b3;
    pf1.u[0] = b4; pf1.u[1] = b5; pf1.u[2] = b6; pf1.u[3] = b7;
    pf0v = pf0.v; pf1v = pf1.v;
}

__device__ __forceinline__ void dostep(int s, const s16x8* kf, const s16x8* vf,
    const s16x8* qfA, const s16x8* qfB, bool doA, bool mA, bool mB,
    f32x16& oA0, f32x16& oA1, f32x16& oB0, f32x16& oB1,
    float& mxA, float& lA, float& mxB, float& lB,
    int qbA, int qbB, int l31, int hi)
{
    int kv0 = s * 32;
    f32x16 stB = fz16();
#pragma unroll
    for (int kd = 0; kd < 4; ++kd) stB = mfma32(kf[kd], qfB[kd], stB);
    if (doA) {
        f32x16 stA = fz16();
#pragma unroll
        for (int kd = 0; kd < 4; ++kd) stA = mfma32(kf[kd], qfA[kd], stA);
        s16x8 pfA0, pfA1;
        sm_step(stA, mxA, lA, oA0, oA1, mA, kv0, qbA, l31, hi, pfA0, pfA1);
        oA0 = mfma32(vf[0], pfA0, oA0);
        oA0 = mfma32(vf[1], pfA1, oA0);
        oA1 = mfma32(vf[2], pfA0, oA1);
        oA1 = mfma32(vf[3], pfA1, oA1);
    }
    s16x8 pfB0, pfB1;
    sm_step(stB, mxB, lB, oB0, oB1, mB, kv0, qbB, l31, hi, pfB0, pfB1);
    oB0 = mfma32(vf[0], pfB0, oB0);
    oB0 = mfma32(vf[1], pfB1, oB0);
    oB1 = mfma32(vf[2], pfB0, oB1);
    oB1 = mfma32(vf[3], pfB1, oB1);
}

__device__ __forceinline__ void attn_epi(unsigned short* epb, const f32x16& o0, const f32x16& o1,
                                         float lrow, int l31, int hi, int lane,
                                         unsigned short* __restrict__ Oo, int qb, int b, int hh)
{
    float lt = lrow + __shfl_xor(lrow, 32);
    float inv = 1.0f / lt;
#pragma unroll
    for (int j = 0; j < 2; ++j) {
        const f32x16& o = j ? o1 : o0;
#pragma unroll
        for (int g = 0; g < 4; ++g) {
            int d0 = j * 32 + g * 8 + hi * 4;
            unsigned lo = cvt_pk_bf16(o[g * 4 + 0] * inv, o[g * 4 + 1] * inv);
            unsigned hw = cvt_pk_bf16(o[g * 4 + 2] * inv, o[g * 4 + 3] * inv);
            unsigned short* p = epb + l31 * 72 + d0;
            *(unsigned*)(p)     = lo;
            *(unsigned*)(p + 2) = hw;
        }
    }
    asm volatile("s_waitcnt lgkmcnt(0)" ::: "memory");
    __builtin_amdgcn_sched_barrier(0);
#pragma unroll
    for (int rr = 0; rr < 4; ++rr) {
        int q2 = rr * 8 + (lane >> 3);
        int d2 = (lane & 7) * 8;
        u32x4 vv = *(const u32x4*)(epb + q2 * 72 + d2);
        *(u32x4*)(Oo + (((long)b * NS + qb + q2) * ND) + hh * NDK + d2) = vv;
    }
}

__global__ __launch_bounds__(256, 2)
void attn_fwd5(const unsigned short* __restrict__ Q,
               const unsigned short* __restrict__ Kt,
               const unsigned short* __restrict__ Vt,
               unsigned short* __restrict__ Oo,
               const int* __restrict__ causalp)
{
    __shared__ unsigned short ep[4][32 * 72];
    int tid = threadIdx.x, w = tid >> 6, lane = tid & 63;
    int l31 = lane & 31, hi = lane >> 5;
    int bh = blockIdx.y;
    int i  = blockIdx.x * 4 + w;          // pair index 0..31
    int causal = *causalp;
    int qbA = i * 32, qbB = (63 - i) * 32;
    int NstB  = causal ? (64 - i) : 64;
    int lastA = causal ? i : 63;
    int diagA = causal ? i : -1;
    int diagB = causal ? (63 - i) : -1;

    const unsigned short* Qh = Q  + bh * (NS * NDK);
    const unsigned short* Kh = Kt + bh * (NS * NDK);
    const unsigned short* Vh = Vt + bh * (NDK * NS);
    const unsigned short* vbase = Vh + l31 * NS + hi * 8;

    s16x8 qfA[4], qfB[4];
#pragma unroll
    for (int kd = 0; kd < 4; ++kd) {
        qfA[kd] = *(const s16x8*)(Qh + (qbA + l31) * NDK + kd * 16 + hi * 8);
        qfB[kd] = *(const s16x8*)(Qh + (qbB + l31) * NDK + kd * 16 + hi * 8);
    }

    f32x16 oA0 = fz16(), oA1 = fz16(), oB0 = fz16(), oB1 = fz16();
    float mxA = -1e30f, lA = 0.f, mxB = -1e30f, lB = 0.f;

    s16x8 k0[4], v0[4], k1[4], v1[4];
    loadKV(Kh, vbase, 0, k0, v0, l31, hi);
    int s = 0;
    while (true) {
        if (s + 1 < NstB) loadKV(Kh, vbase, (s + 1) * 32, k1, v1, l31, hi);
        dostep(s, k0, v0, qfA, qfB, s <= lastA, s == diagA, s == diagB,
               oA0, oA1, oB0, oB1, mxA, lA, mxB, lB, qbA, qbB, l31, hi);
        if (++s == NstB) break;
        if (s + 1 < NstB) loadKV(Kh, vbase, (s + 1) * 32, k0, v0, l31, hi);
        dostep(s, k1, v1, qfA, qfB, s <= lastA, s == diagA, s == diagB,
               oA0, oA1, oB0, oB1, mxA, lA, mxB, lB, qbA, qbB, l31, hi);
        if (++s == NstB) break;
    }

    int b = bh >> 4, hh = bh & 15;
    attn_epi(&ep[w][0], oA0, oA1, lA, l31, hi, lane, Oo, qbA, b, hh);
    attn_epi(&ep[w][0], oB0, oB1, lB, l31, hi, lane, Oo, qbB, b, hh);
}

// ---------------------------------------------------------------- launch
extern "C" void kernel_launch(void* const* d_in, const int* in_sizes, int n_in,
                              void* d_out, int out_size, void* d_ws, size_t ws_size,
                              hipStream_t stream) {
    const void* x  = d_in[0];
    const void* Wq = d_in[1];
    const void* Wk = d_in[2];
    const void* Wv = d_in[3];
    const void* Wo = d_in[4];
    const int* causal = (const int*)d_in[5];

    const long TOK  = (long)NB * NS * ND;
    const long WTOK = (long)ND * ND;
    size_t need = 256 + 4UL * TOK * 2;
    if (ws_size < need) return;

    char* ws = (char*)d_ws;
    int* flag = (int*)ws;
    unsigned short* Qb = (unsigned short*)(ws + 256);
    unsigned short* Kb = Qb + TOK;
    unsigned short* Vb = Kb + TOK;
    unsigned short* XB = Vb + TOK;          // x_bf16; later reused as attn out Ab
    unsigned short* Ab = XB;
    unsigned short* WS1 = Kb + TOK - WTOK;  // dead tail of Kb until K-GEMM writes
    unsigned short* WS2 = Vb + TOK - WTOK;  // dead tail of Vb until V-GEMM writes
    unsigned short* WOB = Qb;               // Qb dead after attention

    detect_dtype<<<1, 64, 0, stream>>>((const unsigned*)x, flag);

    convert_bf16<<<2048, 256, 0, stream>>>(x,  XB,  (int)(TOK / 8),  flag);
    convert_bf16<<<512,  256, 0, stream>>>(Wq, WS1, (int)(WTOK / 8), flag);
    convert_bf16<<<512,  256, 0, stream>>>(Wk, WS2, (int)(WTOK / 8), flag);

    dim3 blk(256);
    // Q = x·Wq^T, scaled 0.125*log2(e) so softmax runs in log2 domain
    gemm2<0, 0, 0><<<dim3(8, 64), blk, 0, stream>>>(XB, WS1, Qb, flag, 0.125f * L2E);
    gemm2<0, 0, 0><<<dim3(8, 64), blk, 0, stream>>>(XB, WS2, Kb, flag, 1.0f);
    gemm2<1, 1, 0><<<dim3(64, 8), blk, 0, stream>>>(Wv, XB, Vb, flag, 1.0f);
    attn_fwd5<<<dim3(8, 64), blk, 0, stream>>>(Qb, Kb, Vb, Ab, causal);
    // Wo -> bf16 into dead Qb, then out-GEMM fully global_load_lds
    convert_bf16<<<512, 256, 0, stream>>>(Wo, WOB, (int)(WTOK / 8), flag);
    gemm2<2, 0, 0><<<dim3(8, 64), blk, 0, stream>>>(Ab, WOB, d_out, flag, 1.0f);
}